// Round 1
// baseline (8166.626 us; speedup 1.0000x reference)
//
#include <hip/hip_runtime.h>
#include <math.h>

namespace {

constexpr int cD = 512;
constexpr int cH = 8;
constexpr int cL = 512;
constexpr int cV = 32000;
constexpr int cNB = 2;
constexpr int cM = 8;      // NB*K
constexpr int cB = 4;
constexpr int cINTER = 1536;
constexpr int cNROWS = cB * cM * cL;  // 16384
constexpr float cSCALE = 22.627416997969522f;  // sqrt(512)
constexpr float cISQ = 0.125f;                  // 1/sqrt(64)

// ---------------------------------------------------------------------------
// Generic NT GEMM:  C[r,c] = epilogue( sum_k A[r,k] * W[c,k] )
// BM=BN=128, BK=16, 256 threads, 8x8 microtile. All dims divide evenly.
// EPI: 0 plain | 1 cand | 2 fusion | 3 +resid | 4 silu(g)*acc
// ---------------------------------------------------------------------------
struct GemmP {
  const float* A; int lda; long long sAz; int divA;
  const float* W; int ldw; long long sWz; int modW;
  float* C; int ldc; long long sCz;
  int Kd;
  const float* resid;   // EPI3: residual, ld = 512
  const float* aux1;    // EPI2: pe_proj ; EPI4: g buffer (== C)
  const float* aux2;    // EPI2: pred_embedding
  const float* aux3;    // EPI2: embed_W
  const float* bvec;    // EPI1: branch_b base ; EPI2: fusion_b
  const int* itok;      // EPI2: inputs
};

template <int EPI>
__global__ __launch_bounds__(256) void gemm_k(GemmP p) {
  const int z = blockIdx.z;
  const float* __restrict__ A = p.A + (long long)(z / p.divA) * p.sAz;
  const float* __restrict__ W = p.W + (long long)(z % p.modW) * p.sWz;
  float* __restrict__ C = p.C + (long long)z * p.sCz;
  const float* bv = nullptr;
  if (EPI == 1 || EPI == 2) bv = p.bvec + (long long)(z % p.modW) * cD;

  const int row0 = blockIdx.y * 128;
  const int col0 = blockIdx.x * 128;
  __shared__ float As[16][132];
  __shared__ float Bs[16][132];
  const int tid = threadIdx.x;
  const int tx = tid & 15;
  const int ty = tid >> 4;

  float acc[8][8];
#pragma unroll
  for (int i = 0; i < 8; ++i)
#pragma unroll
    for (int j = 0; j < 8; ++j) acc[i][j] = 0.0f;

  for (int k0 = 0; k0 < p.Kd; k0 += 16) {
#pragma unroll
    for (int i = 0; i < 2; ++i) {
      const int slot = tid + i * 256;          // 0..511
      const int rr = slot >> 2;                // 0..127
      const int kq = (slot & 3) << 2;          // 0,4,8,12
      float4 a4 = *(const float4*)(A + (long long)(row0 + rr) * p.lda + k0 + kq);
      As[kq + 0][rr] = a4.x; As[kq + 1][rr] = a4.y;
      As[kq + 2][rr] = a4.z; As[kq + 3][rr] = a4.w;
      float4 w4 = *(const float4*)(W + (long long)(col0 + rr) * p.ldw + k0 + kq);
      Bs[kq + 0][rr] = w4.x; Bs[kq + 1][rr] = w4.y;
      Bs[kq + 2][rr] = w4.z; Bs[kq + 3][rr] = w4.w;
    }
    __syncthreads();
#pragma unroll
    for (int kk = 0; kk < 16; ++kk) {
      float av[8], bw[8];
      *(float4*)&av[0] = *(const float4*)&As[kk][ty * 8];
      *(float4*)&av[4] = *(const float4*)&As[kk][ty * 8 + 4];
      *(float4*)&bw[0] = *(const float4*)&Bs[kk][tx * 8];
      *(float4*)&bw[4] = *(const float4*)&Bs[kk][tx * 8 + 4];
#pragma unroll
      for (int i = 0; i < 8; ++i)
#pragma unroll
        for (int j = 0; j < 8; ++j) acc[i][j] = fmaf(av[i], bw[j], acc[i][j]);
    }
    __syncthreads();
  }

#pragma unroll
  for (int i = 0; i < 8; ++i) {
    const int r = row0 + ty * 8 + i;
    long long prow = 0, tokoff = 0;
    if (EPI == 2) {
      const int bb = r >> 12;        // / (M*L)
      const int rem = r & 4095;
      const int mm = rem >> 9;
      const int ll = rem & 511;
      prow = (long long)((bb * cNB + (mm >> 2)) * cL + ll) * cD;
      tokoff = (long long)p.itok[bb * cL + ll] * cD;
    }
    float outv[8];
#pragma unroll
    for (int j = 0; j < 8; ++j) {
      const int c = col0 + tx * 8 + j;
      float v = acc[i][j];
      if (EPI == 1) {
        v = A[(long long)r * p.lda + c] + 0.1f * (v + bv[c]);
      } else if (EPI == 2) {
        const float gsum = v + p.aux1[prow + c] + bv[c];
        const float gate = 1.0f / (1.0f + expf(-gsum));
        v = A[(long long)r * p.lda + c] + gate * p.aux2[prow + c] +
            cSCALE * p.aux3[tokoff + c];
      } else if (EPI == 3) {
        v = p.resid[(long long)r * cD + c] + v;
      } else if (EPI == 4) {
        const float g = p.aux1[(long long)r * p.ldc + c];
        v = (g / (1.0f + expf(-g))) * v;
      }
      outv[j] = v;
    }
    float* cp = C + (long long)r * p.ldc + col0 + tx * 8;
    *(float4*)cp = *(float4*)&outv[0];
    *(float4*)(cp + 4) = *(float4*)&outv[4];
  }
}

// ---------------------------------------------------------------------------
// RoPE table (match numpy float64 build, cast f32)
// ---------------------------------------------------------------------------
__global__ void ropetab_k(float* cosT, float* sinT) {
  const int i = blockIdx.x * 256 + threadIdx.x;  // 0..16383
  if (i >= cL * 32) return;
  const int l = i >> 5;
  const int j = i & 31;
  const double inv = pow(10000.0, -(double)j / 32.0);
  const double a = (double)l * inv;
  const float c = (float)cos(a);
  const float s = (float)sin(a);
  cosT[l * 64 + j] = c; cosT[l * 64 + j + 32] = c;
  sinT[l * 64 + j] = s; sinT[l * 64 + j + 32] = s;
}

// ---------------------------------------------------------------------------
// RoPE apply in-place on q,k halves of qkv buffer (rows x 1536)
// ---------------------------------------------------------------------------
__global__ void rope_k(float* qkv, const float* __restrict__ cosT,
                       const float* __restrict__ sinT) {
  const long long idx = (long long)blockIdx.x * 256 + threadIdx.x;  // 8,388,608
  const int row = (int)(idx >> 9);
  const int pid = (int)(idx & 511);
  const int part = pid >> 8;         // 0=q, 1=k
  const int rem = pid & 255;
  const int hh = rem >> 5;
  const int d = rem & 31;
  const int l = row & 511;
  float* base = qkv + (long long)row * 1536 + part * 512 + hh * 64 + d;
  const float x1 = base[0];
  const float x2 = base[32];
  const float c = cosT[l * 64 + d];
  const float s = sinT[l * 64 + d];
  base[0] = x1 * c - x2 * s;
  base[32] = x2 * c + x1 * s;
}

// ---------------------------------------------------------------------------
// Flash attention: one block per (n, h, 64-row q tile). Online softmax.
// qkv rows: [q(8x64) | k(8x64) | v(8x64)]; out o as (n, l, h*64+d)
// ---------------------------------------------------------------------------
__global__ __launch_bounds__(256) void attn_k(const float* __restrict__ qkv,
                                              const float* __restrict__ bias,
                                              float* __restrict__ o) {
  const int n = blockIdx.z;
  const int hh = blockIdx.y;
  const int q0 = blockIdx.x * 64;
  __shared__ float Qs[64][68];
  __shared__ float KVs[64][68];
  __shared__ float Ps[64][68];
  const int tid = threadIdx.x;
  const int tx = tid & 15;
  const int ty = tid >> 4;

#pragma unroll
  for (int i = 0; i < 4; ++i) {
    const int slot = tid + i * 256;
    const int r = slot >> 4;
    const int dq = (slot & 15) << 2;
    float4 v = *(const float4*)(qkv + (long long)(n * 512 + q0 + r) * 1536 + hh * 64 + dq);
    Qs[dq][r] = v.x; Qs[dq + 1][r] = v.y; Qs[dq + 2][r] = v.z; Qs[dq + 3][r] = v.w;
  }
  float m_i[4], l_i[4], oacc[4][4];
#pragma unroll
  for (int i = 0; i < 4; ++i) {
    m_i[i] = -INFINITY; l_i[i] = 0.0f;
#pragma unroll
    for (int j = 0; j < 4; ++j) oacc[i][j] = 0.0f;
  }
  __syncthreads();

  for (int k0 = 0; k0 < 512; k0 += 64) {
    // K tile (transposed)
#pragma unroll
    for (int i = 0; i < 4; ++i) {
      const int slot = tid + i * 256;
      const int r = slot >> 4;
      const int dq = (slot & 15) << 2;
      float4 v = *(const float4*)(qkv + (long long)(n * 512 + k0 + r) * 1536 + 512 + hh * 64 + dq);
      KVs[dq][r] = v.x; KVs[dq + 1][r] = v.y; KVs[dq + 2][r] = v.z; KVs[dq + 3][r] = v.w;
    }
    __syncthreads();

    float s[4][4];
#pragma unroll
    for (int i = 0; i < 4; ++i)
#pragma unroll
      for (int j = 0; j < 4; ++j) s[i][j] = 0.0f;
    for (int d = 0; d < 64; ++d) {
      float a[4], b[4];
      *(float4*)a = *(const float4*)&Qs[d][ty * 4];
      *(float4*)b = *(const float4*)&KVs[d][tx * 4];
#pragma unroll
      for (int i = 0; i < 4; ++i)
#pragma unroll
        for (int j = 0; j < 4; ++j) s[i][j] = fmaf(a[i], b[j], s[i][j]);
    }
#pragma unroll
    for (int i = 0; i < 4; ++i) {
      float4 bb = *(const float4*)(bias + ((long long)hh * 512 + q0 + ty * 4 + i) * 512 + k0 + tx * 4);
      s[i][0] = fmaf(s[i][0], cISQ, bb.x);
      s[i][1] = fmaf(s[i][1], cISQ, bb.y);
      s[i][2] = fmaf(s[i][2], cISQ, bb.z);
      s[i][3] = fmaf(s[i][3], cISQ, bb.w);
    }
    // online softmax update per q row (shared among the 16 tx lanes)
#pragma unroll
    for (int i = 0; i < 4; ++i) {
      float rmax = fmaxf(fmaxf(s[i][0], s[i][1]), fmaxf(s[i][2], s[i][3]));
      for (int off = 1; off < 16; off <<= 1) rmax = fmaxf(rmax, __shfl_xor(rmax, off));
      const float mnew = fmaxf(m_i[i], rmax);
      const float sc = expf(m_i[i] - mnew);
      const float p0 = expf(s[i][0] - mnew);
      const float p1 = expf(s[i][1] - mnew);
      const float p2 = expf(s[i][2] - mnew);
      const float p3 = expf(s[i][3] - mnew);
      float rs = p0 + p1 + p2 + p3;
      for (int off = 1; off < 16; off <<= 1) rs += __shfl_xor(rs, off);
      l_i[i] = l_i[i] * sc + rs;
      m_i[i] = mnew;
#pragma unroll
      for (int j = 0; j < 4; ++j) oacc[i][j] *= sc;
      float4 pv = make_float4(p0, p1, p2, p3);
      *(float4*)&Ps[ty * 4 + i][tx * 4] = pv;
    }
    __syncthreads();  // Ps complete; everyone done reading K from KVs

    // V tile (direct layout)
#pragma unroll
    for (int i = 0; i < 4; ++i) {
      const int slot = tid + i * 256;
      const int r = slot >> 4;
      const int dq = (slot & 15) << 2;
      float4 v = *(const float4*)(qkv + (long long)(n * 512 + k0 + r) * 1536 + 1024 + hh * 64 + dq);
      *(float4*)&KVs[r][dq] = v;
    }
    __syncthreads();

    for (int k = 0; k < 64; k += 4) {
      float pvals[4][4], vvals[4][4];
#pragma unroll
      for (int t = 0; t < 4; ++t) *(float4*)&vvals[t][0] = *(const float4*)&KVs[k + t][tx * 4];
#pragma unroll
      for (int i = 0; i < 4; ++i) *(float4*)&pvals[i][0] = *(const float4*)&Ps[ty * 4 + i][k];
#pragma unroll
      for (int i = 0; i < 4; ++i)
#pragma unroll
        for (int j = 0; j < 4; ++j)
#pragma unroll
          for (int t = 0; t < 4; ++t) oacc[i][j] = fmaf(pvals[i][t], vvals[t][j], oacc[i][j]);
    }
    __syncthreads();  // before next tile overwrites KVs
  }

#pragma unroll
  for (int i = 0; i < 4; ++i) {
    const float inv = 1.0f / l_i[i];
    float4 ov = make_float4(oacc[i][0] * inv, oacc[i][1] * inv, oacc[i][2] * inv, oacc[i][3] * inv);
    *(float4*)(o + (long long)(n * 512 + q0 + ty * 4 + i) * 512 + hh * 64 + tx * 4) = ov;
  }
}

// ---------------------------------------------------------------------------
// Row RMS norm: out = in * rsqrt(mean(in^2) + 1e-5), rows of 512
// ---------------------------------------------------------------------------
__global__ __launch_bounds__(128) void rms_k(const float* __restrict__ in, float* __restrict__ out) {
  const int row = blockIdx.x;
  const int t = threadIdx.x;
  float4 v = *(const float4*)(in + (long long)row * 512 + t * 4);
  float ss = v.x * v.x + v.y * v.y + v.z * v.z + v.w * v.w;
  for (int off = 1; off < 64; off <<= 1) ss += __shfl_xor(ss, off);
  __shared__ float sred[2];
  if ((t & 63) == 0) sred[t >> 6] = ss;
  __syncthreads();
  const float tot = sred[0] + sred[1];
  const float sc = 1.0f / sqrtf(tot * (1.0f / 512.0f) + 1e-5f);
  float4 ov = make_float4(v.x * sc, v.y * sc, v.z * sc, v.w * sc);
  *(float4*)(out + (long long)row * 512 + t * 4) = ov;
}

// ---------------------------------------------------------------------------
// Value head: vals[bm] = gelu(pooled @ vW1.T + vb1) @ vW2.T + vb2
// ---------------------------------------------------------------------------
__global__ __launch_bounds__(256) void vals_k(const float* __restrict__ h,
                                              const float* __restrict__ vW1,
                                              const float* __restrict__ vb1,
                                              const float* __restrict__ vW2,
                                              const float* __restrict__ vb2,
                                              float* out_vals, float* ws_vals) {
  const int bm = blockIdx.x;  // 0..31
  const int t = threadIdx.x;
  __shared__ float prow[512];
  __shared__ float wsum[4];
  const float* src = h + (long long)bm * (512LL * 512);  // row l=0
  *(float2*)&prow[t * 2] = *(const float2*)&src[t * 2];
  __syncthreads();
  float acc = 0.0f;
  const float* wrow = vW1 + (long long)t * 512;
  for (int d = 0; d < 512; d += 4) {
    float4 wv = *(const float4*)&wrow[d];
    float4 pv = *(const float4*)&prow[d];
    acc = fmaf(wv.x, pv.x, acc); acc = fmaf(wv.y, pv.y, acc);
    acc = fmaf(wv.z, pv.z, acc); acc = fmaf(wv.w, pv.w, acc);
  }
  acc += vb1[t];
  const float g = 0.5f * acc * (1.0f + erff(acc * 0.7071067811865475f));
  float part = g * vW2[t];
  for (int off = 1; off < 64; off <<= 1) part += __shfl_xor(part, off);
  if ((t & 63) == 0) wsum[t >> 6] = part;
  __syncthreads();
  if (t == 0) {
    const float v = wsum[0] + wsum[1] + wsum[2] + wsum[3] + vb2[0];
    out_vals[bm] = v;
    ws_vals[bm] = v;
  }
}

// ---------------------------------------------------------------------------
// Beam selection (tiny): scores, top-2 (stable), q_logits
// ---------------------------------------------------------------------------
__global__ void select_k(const float* __restrict__ ws_vals, const float* __restrict__ beam,
                         const float* __restrict__ h, const float* __restrict__ qW,
                         const float* __restrict__ qb, float* out_topv, float* out_qlog,
                         int* iTopI, int* iBest) {
  const int t = threadIdx.x;
  if (t < cB) {
    const int b = t;
    float sc[8];
    for (int m = 0; m < 8; ++m)
      sc[m] = 0.5f * ws_vals[b * 8 + m] + 0.5f * beam[b * 2 + (m >> 2)];
    int i1 = 0;
    for (int m = 1; m < 8; ++m) if (sc[m] > sc[i1]) i1 = m;
    int i2 = -1;
    for (int m = 0; m < 8; ++m) {
      if (m == i1) continue;
      if (i2 < 0 || sc[m] > sc[i2]) i2 = m;
    }
    out_topv[b * 2] = sc[i1];
    out_topv[b * 2 + 1] = sc[i2];
    iTopI[b * 2] = i1; iTopI[b * 2 + 1] = i2;
    iBest[b] = i1;
    const float* pr = h + (long long)(b * 8 + i1) * (512LL * 512);
    for (int j = 0; j < 2; ++j) {
      float acc = qb[j];
      for (int d = 0; d < 512; ++d) acc = fmaf(pr[d], qW[j * 512 + d], acc);
      out_qlog[b * 2 + j] = acc;
    }
  }
}

// new_z gather: out[(b*NB+nb), l, :] = h[(b*M + top_i[b,nb]), l, :]
__global__ void newz_k(const float* __restrict__ h, const int* __restrict__ iTopI,
                       float* __restrict__ out) {
  const int f = blockIdx.x * 256 + threadIdx.x;  // 0..524287 float4s
  const int e4 = f & 127;
  const int rowz = f >> 7;       // 0..4095
  const int l = rowz & 511;
  const int bnb = rowz >> 9;     // 0..7
  const int b = bnb >> 1;
  const int mi = iTopI[bnb];
  const long long src = ((long long)(b * 8 + mi) * 512 + l) * 512 + e4 * 4;
  *(float4*)(out + (long long)f * 4) = *(const float4*)(h + src);
}

// h_best gather: out[b*L+l, :] = h[(b*M + best[b]), l, :]
__global__ void hbest_k(const float* __restrict__ h, const int* __restrict__ iBest,
                        float* __restrict__ out) {
  const int f = blockIdx.x * 256 + threadIdx.x;  // 0..262143 float4s
  const int e4 = f & 127;
  const int row = f >> 7;        // 0..2047
  const int b = row >> 9;
  const int l = row & 511;
  const long long src = ((long long)(b * 8 + iBest[b]) * 512 + l) * 512 + e4 * 4;
  *(float4*)(out + (long long)f * 4) = *(const float4*)(h + src);
}

// argmax over V per row (first occurrence on ties)
__global__ __launch_bounds__(256) void argmax_k(const float* __restrict__ logits,
                                                int* __restrict__ predTok) {
  const int row = blockIdx.x;
  const float* Lr = logits + (long long)row * cV;
  const int t = threadIdx.x;
  float bv = -INFINITY;
  int bi = 0x7fffffff;
  for (int v = t; v < cV; v += 256) {
    const float x = Lr[v];
    if (x > bv) { bv = x; bi = v; }
  }
  __shared__ float sv[256];
  __shared__ int si[256];
  sv[t] = bv; si[t] = bi;
  __syncthreads();
  for (int s = 128; s > 0; s >>= 1) {
    if (t < s) {
      if (sv[t + s] > sv[t] || (sv[t + s] == sv[t] && si[t + s] < si[t])) {
        sv[t] = sv[t + s]; si[t] = si[t + s];
      }
    }
    __syncthreads();
  }
  if (t == 0) predTok[row] = si[0];
}

// new_pred: out[(b*NB+nb), l, :] = SCALE * pred_embed_W[predTok[b*L+l], :]
__global__ void npred_k(const float* __restrict__ peW, const int* __restrict__ predTok,
                        float* __restrict__ out) {
  const int f = blockIdx.x * 256 + threadIdx.x;  // 0..524287 float4s
  const int e4 = f & 127;
  const int rowz = f >> 7;
  const int l = rowz & 511;
  const int bnb = rowz >> 9;
  const int b = bnb >> 1;
  const int tok = predTok[b * 512 + l];
  float4 v = *(const float4*)(peW + (long long)tok * 512 + e4 * 4);
  v.x *= cSCALE; v.y *= cSCALE; v.z *= cSCALE; v.w *= cSCALE;
  *(float4*)(out + (long long)f * 4) = v;
}

GemmP base_p() {
  GemmP p;
  p.A = nullptr; p.lda = 0; p.sAz = 0; p.divA = 1;
  p.W = nullptr; p.ldw = 0; p.sWz = 0; p.modW = 1;
  p.C = nullptr; p.ldc = 0; p.sCz = 0;
  p.Kd = 0;
  p.resid = nullptr; p.aux1 = nullptr; p.aux2 = nullptr; p.aux3 = nullptr;
  p.bvec = nullptr; p.itok = nullptr;
  return p;
}

void launch_gemm(int epi, const GemmP& p, int nblk, int mblk, int zblk, hipStream_t s) {
  dim3 g(nblk, mblk, zblk), b(256, 1, 1);
  switch (epi) {
    case 0: gemm_k<0><<<g, b, 0, s>>>(p); break;
    case 1: gemm_k<1><<<g, b, 0, s>>>(p); break;
    case 2: gemm_k<2><<<g, b, 0, s>>>(p); break;
    case 3: gemm_k<3><<<g, b, 0, s>>>(p); break;
    case 4: gemm_k<4><<<g, b, 0, s>>>(p); break;
  }
}

}  // namespace

extern "C" void kernel_launch(void* const* d_in, const int* in_sizes, int n_in,
                              void* d_out, int out_size, void* d_ws, size_t ws_size,
                              hipStream_t stream) {
  const float* z_in     = (const float*)d_in[0];
  const float* pred_emb = (const float*)d_in[1];
  const float* beam     = (const float*)d_in[2];
  const int*   inputs   = (const int*)d_in[3];
  const float* embed_W  = (const float*)d_in[4];
  const float* pembed_W = (const float*)d_in[5];
  const float* branch_W = (const float*)d_in[6];
  const float* branch_b = (const float*)d_in[7];
  const float* fusion_W = (const float*)d_in[8];
  const float* fusion_b = (const float*)d_in[9];
  const float* qkv_w    = (const float*)d_in[10];
  const float* o_w      = (const float*)d_in[11];
  const float* gu_w     = (const float*)d_in[12];
  const float* down_w   = (const float*)d_in[13];
  const float* bias     = (const float*)d_in[14];
  const float* vW1      = (const float*)d_in[15];
  const float* vb1      = (const float*)d_in[16];
  const float* vW2      = (const float*)d_in[17];
  const float* vb2      = (const float*)d_in[18];
  const float* qW       = (const float*)d_in[19];
  const float* qb       = (const float*)d_in[20];
  const float* lm_W     = (const float*)d_in[21];
  float* out = (float*)d_out;

  // workspace layout (floats); total ~201.6 MB
  float* w = (float*)d_ws;
  float* cosT    = w;                 // 32768
  float* sinT    = w + 32768;         // 32768
  float* vals_ws = w + 65536;         // 32
  int*   iTopI   = (int*)(w + 65568); // 8
  int*   iBest   = iTopI + 8;         // 4
  int*   iPred   = iBest + 4;         // 2048
  float* hbuf = w + 67840;            // 8,388,608   (h)
  float* w1   = hbuf + 8388608;       // 25,165,824  (qkv / gu / cand)
  float* w2   = w1 + 25165824;        // 8,388,608   (o / pe_proj / h_best)
  float* w3   = w2 + 8388608;         // 8,388,608   (pre-RMS y)
  float* cand   = w1;
  float* peproj = w2;
  float* hbest  = w2;

  float* out_newz    = out;
  float* out_newpred = out + 2097152;
  float* out_topv    = out + 4194304;
  float* out_logits  = out + 4194312;
  float* out_qlog    = out + 69730312;
  float* out_vals    = out + 69730320;

  // 1. RoPE table
  ropetab_k<<<64, 256, 0, stream>>>(cosT, sinT);

  // 2. cand[z=n*K+k] = zf[n] + 0.1*(zf[n] @ branch_W[k].T + branch_b[k])
  {
    GemmP p = base_p();
    p.A = z_in; p.lda = 512; p.sAz = 262144; p.divA = 4;
    p.W = branch_W; p.ldw = 512; p.sWz = 262144; p.modW = 4;
    p.C = cand; p.ldc = 512; p.sCz = 262144;
    p.Kd = 512; p.bvec = branch_b;
    launch_gemm(1, p, 4, 4, 32, stream);
  }
  // 3. pe_proj = pred_embedding @ fusion_W[:,512:].T   (4096 x 512)
  {
    GemmP p = base_p();
    p.A = pred_emb; p.lda = 512;
    p.W = fusion_W + 512; p.ldw = 1024;
    p.C = peproj; p.ldc = 512;
    p.Kd = 512;
    launch_gemm(0, p, 4, 32, 1, stream);
  }
  // 4. fusion: h = cand + sigmoid(cand@Wc.T + pe_proj + fb)*pe + SCALE*emb[tok]
  {
    GemmP p = base_p();
    p.A = cand; p.lda = 512;
    p.W = fusion_W; p.ldw = 1024;
    p.C = hbuf; p.ldc = 512;
    p.Kd = 512;
    p.aux1 = peproj; p.aux2 = pred_emb; p.aux3 = embed_W;
    p.bvec = fusion_b; p.itok = inputs;
    launch_gemm(2, p, 4, 128, 1, stream);
  }

  // transformer layers
  for (int i = 0; i < 4; ++i) {
    // qkv
    {
      GemmP p = base_p();
      p.A = hbuf; p.lda = 512;
      p.W = qkv_w + (long long)i * 1536 * 512; p.ldw = 512;
      p.C = w1; p.ldc = 1536;
      p.Kd = 512;
      launch_gemm(0, p, 12, 128, 1, stream);
    }
    // rope on q,k
    rope_k<<<32768, 256, 0, stream>>>(w1, cosT, sinT);
    // attention
    {
      dim3 g(8, 8, 32), b(256, 1, 1);
      attn_k<<<g, b, 0, stream>>>(w1, bias, w2);
    }
    // o_proj + residual -> w3 ; rms -> h
    {
      GemmP p = base_p();
      p.A = w2; p.lda = 512;
      p.W = o_w + (long long)i * 262144; p.ldw = 512;
      p.C = w3; p.ldc = 512;
      p.Kd = 512; p.resid = hbuf;
      launch_gemm(3, p, 4, 128, 1, stream);
    }
    rms_k<<<16384, 128, 0, stream>>>(w3, hbuf);
    // g = h @ gu_w[:INTER].T
    {
      GemmP p = base_p();
      p.A = hbuf; p.lda = 512;
      p.W = gu_w + (long long)i * 3072 * 512; p.ldw = 512;
      p.C = w1; p.ldc = 1536;
      p.Kd = 512;
      launch_gemm(0, p, 12, 128, 1, stream);
    }
    // t = silu(g) * (h @ gu_w[INTER:].T)   in-place into w1
    {
      GemmP p = base_p();
      p.A = hbuf; p.lda = 512;
      p.W = gu_w + (long long)i * 3072 * 512 + 1536 * 512; p.ldw = 512;
      p.C = w1; p.ldc = 1536;
      p.Kd = 512; p.aux1 = w1;
      launch_gemm(4, p, 12, 128, 1, stream);
    }
    // down + residual -> w3 ; rms -> h
    {
      GemmP p = base_p();
      p.A = w1; p.lda = 1536;
      p.W = down_w + (long long)i * 512 * 1536; p.ldw = 1536;
      p.C = w3; p.ldc = 512;
      p.Kd = 1536; p.resid = hbuf;
      launch_gemm(3, p, 4, 128, 1, stream);
    }
    rms_k<<<16384, 128, 0, stream>>>(w3, hbuf);
  }

  // value head + selection
  vals_k<<<32, 256, 0, stream>>>(hbuf, vW1, vb1, vW2, vb2, out_vals, vals_ws);
  select_k<<<1, 64, 0, stream>>>(vals_ws, beam, hbuf, qW, qb, out_topv, out_qlog,
                                 iTopI, iBest);
  newz_k<<<2048, 256, 0, stream>>>(hbuf, iTopI, out_newz);
  hbest_k<<<1024, 256, 0, stream>>>(hbuf, iBest, hbest);

  // logits = h_best @ lm_W.T  (2048 x 32000)
  {
    GemmP p = base_p();
    p.A = hbest; p.lda = 512;
    p.W = lm_W; p.ldw = 512;
    p.C = out_logits; p.ldc = 32000;
    p.Kd = 512;
    launch_gemm(0, p, 250, 16, 1, stream);
  }
  argmax_k<<<2048, 256, 0, stream>>>(out_logits, iPred);
  npred_k<<<2048, 256, 0, stream>>>(pembed_W, iPred, out_newpred);
}